// Round 14
// baseline (251.870 us; speedup 1.0000x reference)
//
#include <hip/hip_runtime.h>

typedef _Float16 half8 __attribute__((ext_vector_type(8)));
typedef float floatx4 __attribute__((ext_vector_type(4)));

constexpr int Bn = 16, Cn = 256, Hn = 64, Wn = 96;
constexpr int HW = Hn * Wn;          // 6144
constexpr int Dn = 21, ND = Dn * Dn; // 441
constexpr int PH = Hn + 40;          // 104
constexpr int PW = Wn + 40;          // 136
constexpr int PHW = PH * PW;         // 14144
constexpr int TY = 8, TX = 16;
constexpr int NTY = Hn / TY;         // 8
constexpr int NTX = Wn / TX;         // 6
constexpr int NJ = (TX + 40) / 2;    // 28 window cols per parity
constexpr int GP = 260;              // G pitch f16
// SMEM: stage 4 waves x 2 bufs x 4KB = 32KB; G 2x32x260x2 = 33,280B (union)
constexpr int SMEM_BYTES = 33280;    // -> 4 wg/CU

constexpr size_t F1T_BYTES = (size_t)Bn * HW * Cn * 2;   // 50,331,648
constexpr size_t F2T_BYTES = (size_t)Bn * PHW * Cn * 2;  // 115,867,648
constexpr size_t WS_NEEDED = F1T_BYTES + F2T_BYTES;

constexpr int F1_BLKS = Bn * (HW / 64);    // 1536
constexpr int F2_BLKS = Bn * (PHW / 64);   // 3536

// ---------------- pass 1 (merged): f32 BCHW -> f16 pixel-major ------------
__global__ __launch_bounds__(256)
void tconv_all(const float* __restrict__ f1, const float* __restrict__ f2,
               _Float16* __restrict__ f1t, _Float16* __restrict__ f2t) {
  int blk = blockIdx.x;
  const int t = threadIdx.x;
  const int pxl = t >> 2;            // 0..63
  const int g = t & 3;
  if (blk < F1_BLKS) {
    const int b = blk / (HW / 64);
    const int px = (blk % (HW / 64)) * 64 + pxl;
    const float* src = f1 + (size_t)b * Cn * HW + px;
    _Float16* dst = f1t + ((size_t)b * HW + px) * Cn;
#pragma unroll
    for (int it = 0; it < 8; ++it) {
      const int c0 = (g + it * 4) * 8;
      half8 v;
#pragma unroll
      for (int k = 0; k < 8; ++k)
        v[k] = (_Float16)src[(size_t)(c0 + k) * HW];
      *(half8*)(dst + c0) = v;
    }
  } else {
    blk -= F1_BLKS;
    const int b = blk / (PHW / 64);
    const int ppx = (blk % (PHW / 64)) * 64 + pxl;
    const int y = ppx / PW;
    const int x = ppx - y * PW;
    const int yy = y - 20, xx = x - 20;
    const bool valid = (yy >= 0) & (yy < Hn) & (xx >= 0) & (xx < Wn);
    const float* src = f2 + (size_t)b * Cn * HW + (valid ? (yy * Wn + xx) : 0);
    _Float16* dst = f2t + ((size_t)b * PHW + ppx) * Cn;
#pragma unroll
    for (int it = 0; it < 8; ++it) {
      const int c0 = (g + it * 4) * 8;
      half8 v;
#pragma unroll
      for (int k = 0; k < 8; ++k) {
        const float f = src[(size_t)(c0 + k) * HW];
        v[k] = (_Float16)(valid ? f : 0.0f);
      }
      *(half8*)(dst + c0) = v;
    }
  }
}

// global->LDS DMA; lds offset is a readfirstlane'd uniform (r8 lesson)
#define GLLDS(gp, lo) \
  __builtin_amdgcn_global_load_lds( \
      (const __attribute__((address_space(1))) void*)(gp), \
      (__attribute__((address_space(3))) void*)(uintptr_t)(lo), 16, 0, 0)
// asm ds_read: opaque to the LDS-DMA alias tracker (C++ read would trigger
// a conservative vmcnt(0) and kill the pipeline)
#define DSREAD(dst, addr, OFFSTR) \
  asm volatile("ds_read_b128 %0, %1 offset:" OFFSTR : "=v"(dst) : "v"(addr));

// ---------------- pass 2: half-slice pipelined staged MFMA ----------------
// corr8's counted-vmcnt wave-private pipeline + corr7's 4 wg/CU occupancy.
// 16 stages = (K-slice s, tile-group g): stage h stages 4 tiles (4KB) into
// buffer g; group 0 also loads the slice's A fragments. vmcnt(4/6) keeps
// stage h+1 in flight across stage h's compute. No barriers in the loop.
__global__ __launch_bounds__(256, 4)
void corr9(const _Float16* __restrict__ f1t, const _Float16* __restrict__ f2t,
           float* __restrict__ out) {
  __shared__ __align__(16) char SMEM[SMEM_BYTES];

  // bijective XCD swizzle: 6144 wgs = 8 XCDs x 768 contiguous
  int bid = (int)blockIdx.x;
  bid = (bid & 7) * 768 + (bid >> 3);
  const int tx = bid % NTX;
  int tmp = bid / NTX;
  const int ty = tmp % NTY;
  tmp /= NTY;
  const int qa = tmp & 1;
  tmp >>= 1;
  const int chunk = tmp & 3;
  const int b = tmp >> 2;
  const int y0 = ty * TY, x0 = tx * TX;

  // dy chunks (6,5,5,5): dyLo 0,6,11,16; window rows = r+3
  const int r = (chunk == 0) ? 6 : 5;
  const int dyLo = (chunk == 0) ? 0 : (1 + 5 * chunk);
  const int rows = r + 3;                 // 9 / 8
  const int NNc = rows * NJ;              // 252 / 224
  const int ndch = r * Dn;                // 126 / 105

  const int t = threadIdx.x;
  const int lane = t & 63;
  const int wave = t >> 6;
  const int l15 = lane & 15;
  const int lk = lane >> 4;
  const int qb = wave >> 1;               // waves 0,1 -> qb0; 2,3 -> qb1
  const int half = wave & 1;              // tile-range half

  const _Float16* f1b = f1t + (size_t)b * HW * Cn;
  const _Float16* f2b = f2t + (size_t)b * PHW * Cn;
  const float invc = 1.0f / 256.0f;

  // wave-private stage region: 8KB per wave (2 x 4KB buffers)
  const unsigned wbase = __builtin_amdgcn_readfirstlane((unsigned)(wave * 8192));
  const unsigned roff = (unsigned)(l15 * 64 + lk * 16);

  // per-tile global base: DMA k of group g stages tile (half*8 + g*4 + k);
  // lane covers slot (lane>>2), channel-quarter (lane&3)
  const _Float16* g[8];
#pragma unroll
  for (int k = 0; k < 8; ++k) {
    const int tile = half * 8 + k;
    int n = tile * 16 + (lane >> 2);
    if (n >= NNc) n = 0;                  // clamp: dup data, deposit guarded
    const int i = n / NJ, j = n % NJ;
    const int py = y0 + qa + 2 * (i + dyLo);
    const int px = x0 + qb + 2 * j;
    g[k] = f2b + (size_t)(py * PW + px) * Cn + (lane & 3) * 8;
  }
  // A fragment pointers (m-tile0 = rows 0..15, m-tile1 = +4 spatial rows)
  const int ay = y0 + qa + 2 * (l15 >> 3);
  const int ax = x0 + qb + 2 * (l15 & 7);
  const _Float16* ap0 = f1b + (size_t)(ay * Wn + ax) * Cn + lk * 8;
  const _Float16* ap1 = ap0 + (size_t)4 * Wn * Cn;

  floatx4 acc0[8], acc1[8];
#pragma unroll
  for (int i = 0; i < 8; ++i) {
    acc0[i] = {0.f, 0.f, 0.f, 0.f};
    acc1[i] = {0.f, 0.f, 0.f, 0.f};
  }
  half8 aA0, aA1, aB0, aB1;               // A double-buffer by slice parity

  // stage h: slice s=h>>1, group gg=h&1, buffer gg, K-byte offset s*64
  auto ISSUE = [&](int h, half8& A0, half8& A1) {
    const int s = h >> 1, gg = h & 1;
    const int kb = s * 64;
    const unsigned pbuf = wbase + (unsigned)(gg * 4096);
#pragma unroll
    for (int k = 0; k < 4; ++k)
      GLLDS((const char*)g[gg * 4 + k] + kb, pbuf + (unsigned)(k * 1024));
    if (gg == 0) {
      asm volatile("global_load_dwordx4 %0, %1, off"
                   : "=v"(A0) : "v"((const char*)ap0 + kb));
      asm volatile("global_load_dwordx4 %0, %1, off"
                   : "=v"(A1) : "v"((const char*)ap1 + kb));
    }
  };
  auto COMPUTE = [&](int h, const half8& A0, const half8& A1) {
    const int gg = h & 1;
    const unsigned ra = wbase + (unsigned)(gg * 4096) + roff;
    half8 bf[4];
    DSREAD(bf[0], ra, "0")    DSREAD(bf[1], ra, "1024")
    DSREAD(bf[2], ra, "2048") DSREAD(bf[3], ra, "3072")
    asm volatile("s_waitcnt lgkmcnt(0)");
    __builtin_amdgcn_sched_barrier(0);    // rule 18: MFMA must not hoist
#pragma unroll
    for (int k = 0; k < 4; ++k) {
      const int ti = gg * 4 + k;
      acc0[ti] = __builtin_amdgcn_mfma_f32_16x16x32_f16(A0, bf[k], acc0[ti], 0, 0, 0);
      acc1[ti] = __builtin_amdgcn_mfma_f32_16x16x32_f16(A1, bf[k], acc1[ti], 0, 0, 0);
    }
  };

  // ---- pipelined loop over 16 stages, 2-deep, counted vmcnt, no barriers
  ISSUE(0, aA0, aA1);                     // slice0 group0 (+A slice0 -> aA)
  ISSUE(1, aA0, aA1);                     // slice0 group1 (no A write)
#pragma unroll
  for (int h = 0; h < 16; ++h) {
    // wait: stage h done; stage h+1 (4 loads if odd-group, 6 if even) in flight
    if (h == 15)     { asm volatile("s_waitcnt vmcnt(0)" ::: "memory"); }
    else if (h & 1)  { asm volatile("s_waitcnt vmcnt(6)" ::: "memory"); }
    else             { asm volatile("s_waitcnt vmcnt(4)" ::: "memory"); }
    __builtin_amdgcn_sched_barrier(0);
    if (((h >> 1) & 1) == 0) COMPUTE(h, aA0, aA1);
    else                     COMPUTE(h, aB0, aB1);
    if (h + 2 < 16) {
      // ISSUE(h+2): A slot for slice (h+2)>>1, parity ((h+2)>>1)&1
      if ((((h + 2) >> 1) & 1) == 0) ISSUE(h + 2, aA0, aA1);
      else                           ISSUE(h + 2, aB0, aB1);
    }
  }
  __syncthreads();                        // stage region becomes G

  // ---- deposit G (pre-scaled f16) into LDS
  _Float16* const Gh = (_Float16*)SMEM;   // G[qb][m][n] at (qb*32+m)*GP + n
#pragma unroll
  for (int ti = 0; ti < 8; ++ti) {
    const int tile = half * 8 + ti;
    const int n = tile * 16 + l15;
    if (n < NNc) {
#pragma unroll
      for (int rr2 = 0; rr2 < 4; ++rr2) {
        Gh[(qb * 32 + 4 * lk + rr2) * GP + n]      = (_Float16)(acc0[ti][rr2] * invc);
        Gh[(qb * 32 + 16 + 4 * lk + rr2) * GP + n] = (_Float16)(acc1[ti][rr2] * invc);
      }
    }
  }
  __syncthreads();

  // ---- merged epilogue (r10/r12/r13 verified): full 64B lines
  {
    const int niter = (ndch + 15) >> 4;
    const int dsub = t >> 4;
    const int alpha = (t >> 2) & 3;
    const int xq = t & 3;
    const int yy = y0 + qa + 2 * alpha;
    float* ob = out + (size_t)b * ND * HW + yy * Wn + x0 + xq * 4;
    const int m0 = alpha * 8 + xq * 2;
    for (int q = 0; q < niter; ++q) {
      const int dch = q * 16 + dsub;
      if (dch < ndch) {
        const unsigned dyl = (unsigned)dch / 21u;
        const int dx = dch - (int)dyl * 21;
        const int dy = dyLo + (int)dyl;
        const int col = ((int)dyl + alpha) * NJ + xq * 2 + dx;
        floatx4 v;
        v[0] = (float)Gh[(0 * 32 + m0) * GP + col];
        v[1] = (float)Gh[(1 * 32 + m0) * GP + col];
        v[2] = (float)Gh[(0 * 32 + m0 + 1) * GP + col + 1];
        v[3] = (float)Gh[(1 * 32 + m0 + 1) * GP + col + 1];
        __builtin_nontemporal_store(v, (floatx4*)(ob + (size_t)(dy * Dn + dx) * HW));
      }
    }
  }
}

// ---------------- fallback (round-1 kernel) if ws too small ---------------
constexpr int FTY = 8, FTX = 8;
constexpr int FNTY = Hn / FTY, FNTX = Wn / FTX;
constexpr int FNJ = 24, FNTILES = 36, FGP = 580;

__global__ __launch_bounds__(256, 4)
void corr_fallback(const float* __restrict__ f1, const float* __restrict__ f2,
                   float* __restrict__ out) {
  __shared__ float G[16 * FGP];
  const int bid = blockIdx.x;
  const int cls = bid & 3;
  const int t2 = bid >> 2;
  const int tx = t2 % FNTX;
  const int t3 = t2 / FNTX;
  const int ty = t3 % FNTY;
  const int b = t3 / FNTY;
  const int qa = cls >> 1, qb = cls & 1;
  const int y0 = ty * FTY, x0 = tx * FTX;
  const int lane = threadIdx.x & 63;
  const int wave = threadIdx.x >> 6;
  const int l15 = lane & 15;
  const int lk = lane >> 4;
  const float* f1b = f1 + b * (Cn * HW);
  const float* f2b = f2 + b * (Cn * HW);
  const int ay = y0 + qa + 2 * (l15 >> 2);
  const int ax = x0 + qb + 2 * (l15 & 3);
  const float* f1p = f1b + ay * Wn + ax;
  half8 afrag[8];
#pragma unroll
  for (int ks = 0; ks < 8; ++ks)
#pragma unroll
    for (int tt = 0; tt < 8; ++tt)
      afrag[ks][tt] = (_Float16)f1p[(ks * 32 + lk * 8 + tt) * HW];
  const int nt0 = wave * (FNTILES / 4);
  for (int nt = nt0; nt < nt0 + FNTILES / 4; ++nt) {
    const unsigned n = nt * 16 + l15;
    const int i = n / (unsigned)FNJ;
    const int j = n % (unsigned)FNJ;
    const int y2 = y0 - 20 + qa + 2 * i;
    const int x2 = x0 - 20 + qb + 2 * j;
    const bool inb = (y2 >= 0) & (y2 < Hn) & (x2 >= 0) & (x2 < Wn);
    const float* f2p = f2b + (inb ? (y2 * Wn + x2) : 0);
    floatx4 acc = {0.f, 0.f, 0.f, 0.f};
#pragma unroll
    for (int ks = 0; ks < 8; ++ks) {
      half8 bfrag;
#pragma unroll
      for (int tt = 0; tt < 8; ++tt) {
        const float v = f2p[(ks * 32 + lk * 8 + tt) * HW];
        bfrag[tt] = (_Float16)(inb ? v : 0.0f);
      }
      acc = __builtin_amdgcn_mfma_f32_16x16x32_f16(afrag[ks], bfrag, acc, 0, 0, 0);
    }
#pragma unroll
    for (int r = 0; r < 4; ++r)
      G[(4 * lk + r) * FGP + n] = acc[r];
  }
  __syncthreads();
  float* outb = out + b * (ND * HW);
  const float invc = 1.0f / 256.0f;
  for (int o = threadIdx.x; o < ND * 16; o += 256) {
    const int d = o >> 4;
    const int m = o & 15;
    const int dy = (unsigned)d / 21u;
    const int dx = (unsigned)d % 21u;
    const int alpha = m >> 2, beta = m & 3;
    const float val = G[m * FGP + (alpha + dy) * FNJ + (beta + dx)] * invc;
    outb[d * HW + (y0 + qa + 2 * alpha) * Wn + (x0 + qb + 2 * beta)] = val;
  }
}

extern "C" void kernel_launch(void* const* d_in, const int* in_sizes, int n_in,
                              void* d_out, int out_size, void* d_ws, size_t ws_size,
                              hipStream_t stream) {
  const float* f1 = (const float*)d_in[0];
  const float* f2 = (const float*)d_in[1];
  float* out = (float*)d_out;
  if (ws_size >= WS_NEEDED) {
    _Float16* f1t = (_Float16*)d_ws;
    _Float16* f2t = (_Float16*)((char*)d_ws + F1T_BYTES);
    tconv_all<<<dim3(F1_BLKS + F2_BLKS), dim3(256), 0, stream>>>(f1, f2, f1t, f2t);
    corr9<<<dim3(Bn * 2 * NTY * NTX * 4), dim3(256), 0, stream>>>(f1t, f2t, out);
  } else {
    corr_fallback<<<dim3(Bn * FNTY * FNTX * 4), dim3(256), 0, stream>>>(f1, f2, out);
  }
}

// Round 15
// 240.899 us; speedup vs baseline: 1.0455x; 1.0455x over previous
//
#include <hip/hip_runtime.h>

typedef _Float16 half8 __attribute__((ext_vector_type(8)));
typedef float floatx4 __attribute__((ext_vector_type(4)));

constexpr int Bn = 16, Cn = 256, Hn = 64, Wn = 96;
constexpr int HW = Hn * Wn;          // 6144
constexpr int Dn = 21, ND = Dn * Dn; // 441
constexpr int PH = Hn + 40;          // 104
constexpr int PW = Wn + 40;          // 136
constexpr int PHW = PH * PW;         // 14144
constexpr int TY = 8, TX = 16;
constexpr int NTY = Hn / TY;         // 8
constexpr int NTX = Wn / TX;         // 6
constexpr int NJ = (TX + 40) / 2;    // 28 window cols per parity
constexpr int GP = 260;              // G pitch f16
// SMEM: stage 2 qb x 16,384 B = 32,768 B; G 2x32x260x2 = 33,280 B (union)
constexpr int SMEM_BYTES = 33280;    // -> 4 wg/CU
// f2t2 layout [b][ks:8][qb:2][py:104][cx:68][32ch f16] -- per-(qb,slice)
// window rows are 28 contiguous 64B slots (28*64=1792B/row, rows contiguous)
constexpr size_t QB_STRIDE  = (size_t)PH * 68 * 64;      // 452,608 B
constexpr size_t KS_STRIDE  = 2 * QB_STRIDE;             // 905,216 B
constexpr size_t B2_STRIDE  = 8 * KS_STRIDE;             // 7,241,728 B

constexpr size_t F1T_BYTES = (size_t)Bn * HW * Cn * 2;   // 50,331,648
constexpr size_t F2T_BYTES = (size_t)Bn * B2_STRIDE;     // 115,867,648
constexpr size_t WS_NEEDED = F1T_BYTES + F2T_BYTES;

constexpr int F1_BLKS = Bn * (HW / 64);    // 1536
constexpr int F2_BLKS = Bn * (PHW / 64);   // 3536

// ---------------- pass 1 (merged): f32 BCHW -> f16 (two layouts) ----------
__global__ __launch_bounds__(256)
void tconv_all(const float* __restrict__ f1, const float* __restrict__ f2,
               _Float16* __restrict__ f1t, _Float16* __restrict__ f2t2) {
  int blk = blockIdx.x;
  const int t = threadIdx.x;
  const int pxl = t >> 2;            // 0..63
  const int g = t & 3;
  if (blk < F1_BLKS) {
    // f1 -> pixel-major [B][HW][256] (A operand; unchanged)
    const int b = blk / (HW / 64);
    const int px = (blk % (HW / 64)) * 64 + pxl;
    const float* src = f1 + (size_t)b * Cn * HW + px;
    _Float16* dst = f1t + ((size_t)b * HW + px) * Cn;
#pragma unroll
    for (int it = 0; it < 8; ++it) {
      const int c0 = (g + it * 4) * 8;
      half8 v;
#pragma unroll
      for (int k = 0; k < 8; ++k)
        v[k] = (_Float16)src[(size_t)(c0 + k) * HW];
      *(half8*)(dst + c0) = v;
    }
  } else {
    // f2 -> K-slice-major padded [b][ks][qb][py][cx][32]
    blk -= F1_BLKS;
    const int b = blk / (PHW / 64);
    const int ppx = (blk % (PHW / 64)) * 64 + pxl;
    const int py = ppx / PW;
    const int px = ppx - py * PW;
    const int qb = px & 1;
    const int cx = px >> 1;
    const int yy = py - 20, xx = px - 20;
    const bool valid = (yy >= 0) & (yy < Hn) & (xx >= 0) & (xx < Wn);
    const float* src = f2 + (size_t)b * Cn * HW + (valid ? (yy * Wn + xx) : 0);
#pragma unroll
    for (int h = 0; h < 2; ++h) {
      const int ks = g + h * 4;
      _Float16* dst = (_Float16*)((char*)f2t2 + (size_t)b * B2_STRIDE
                                  + (size_t)ks * KS_STRIDE + (size_t)qb * QB_STRIDE
                                  + ((size_t)py * 68 + cx) * 64);
#pragma unroll
      for (int q = 0; q < 4; ++q) {
        half8 v;
#pragma unroll
        for (int k = 0; k < 8; ++k) {
          const float f = src[(size_t)(ks * 32 + q * 8 + k) * HW];
          v[k] = (_Float16)(valid ? f : 0.0f);
        }
        *(half8*)(dst + q * 8) = v;
      }
    }
  }
}

// global->LDS DMA; lds offset is a readfirstlane'd uniform (r8 lesson)
#define GLLDS(gp, lo) \
  __builtin_amdgcn_global_load_lds( \
      (const __attribute__((address_space(1))) void*)(gp), \
      (__attribute__((address_space(3))) void*)(uintptr_t)(lo), 16, 0, 0)

// ---------------- pass 2: contiguous-staged MFMA (corr7 cadence) ----------
// One wg = (b, qa, 8x16 tile, dy-chunk), BOTH x-parity classes.
// Per K-slice: 32 coalesced 1KB DMAs stage both qb windows (contiguous rows)
// -> barrier (vmcnt(0) drain) -> conflict-free b128 LDS reads + MFMA into
// resident acc -> barrier. Only the ACCESS PATTERN differs from corr7/9
// (r14 showed schedule changes are neutral; scattered 64B segments are the
// hypothesized wall).
__global__ __launch_bounds__(256, 4)
void corr10(const _Float16* __restrict__ f1t, const _Float16* __restrict__ f2t2,
            float* __restrict__ out) {
  __shared__ __align__(16) char SMEM[SMEM_BYTES];

  // bijective XCD swizzle: 6144 wgs = 8 XCDs x 768 contiguous
  int bid = (int)blockIdx.x;
  bid = (bid & 7) * 768 + (bid >> 3);
  const int tx = bid % NTX;
  int tmp = bid / NTX;
  const int ty = tmp % NTY;
  tmp /= NTY;
  const int qa = tmp & 1;
  tmp >>= 1;
  const int chunk = tmp & 3;
  const int b = tmp >> 2;
  const int y0 = ty * TY, x0 = tx * TX;

  // dy chunks (6,5,5,5): dyLo 0,6,11,16; window rows = r+3
  const int r = (chunk == 0) ? 6 : 5;
  const int dyLo = (chunk == 0) ? 0 : (1 + 5 * chunk);
  const int rows = r + 3;                 // 9 / 8
  const int NNc = rows * NJ;              // 252 / 224
  const int ndch = r * Dn;                // 126 / 105
  const int wbytes = rows * 1792;         // contiguous window bytes per qb

  const int t = threadIdx.x;
  const int lane = t & 63;
  const int wave = t >> 6;
  const int l15 = lane & 15;
  const int lk = lane >> 4;
  const int qbR = wave >> 1;              // read/stage qb of this wave
  const int half = wave & 1;              // tile half / stage half

  const _Float16* f1b = f1t + (size_t)b * HW * Cn;
  const char* f2base = (const char*)f2t2 + (size_t)b * B2_STRIDE
                       + (size_t)qbR * QB_STRIDE;   // ks=0 plane for this qb
  const float invc = 1.0f / 256.0f;

  // stage dest: DMA j of wave w -> LDS qbR*16384 + (half*8+j)*1024 (linear)
  const unsigned wdest = __builtin_amdgcn_readfirstlane((unsigned)(wave * 8192));

  // stage src (ks=0): byte off in window = half*8192 + j*1024 + lane*16
  const char* src0[8];
#pragma unroll
  for (int j = 0; j < 8; ++j) {
    int off = half * 8192 + j * 1024 + lane * 16;
    if (off >= wbytes) off = 0;           // clamp: dup load, lands in LDS pad
    const int row = off / 1792;
    const int cb = off - row * 1792;
    const int py = y0 + qa + 2 * (row + dyLo);
    src0[j] = f2base + ((size_t)py * 68 + (x0 >> 1)) * 64 + cb;
  }

  // per-tile LDS read offsets: slot n at qbR*16384 + n*64 (+ lk*16)
  unsigned rdoff[8];
#pragma unroll
  for (int ti = 0; ti < 8; ++ti) {
    const int n = (half * 8 + ti) * 16 + l15;
    rdoff[ti] = (unsigned)(qbR * 16384 + n * 64 + lk * 16);
  }

  // A fragment pointers (m-tile0 rows 0..15, m-tile1 +4 spatial rows)
  const int ay = y0 + qa + 2 * (l15 >> 3);
  const int ax = x0 + qbR + 2 * (l15 & 7);
  const _Float16* ap0 = f1b + (size_t)(ay * Wn + ax) * Cn + lk * 8;
  const _Float16* ap1 = ap0 + (size_t)4 * Wn * Cn;

  floatx4 acc0[8], acc1[8];
#pragma unroll
  for (int i = 0; i < 8; ++i) {
    acc0[i] = {0.f, 0.f, 0.f, 0.f};
    acc1[i] = {0.f, 0.f, 0.f, 0.f};
  }

  for (int ks = 0; ks < 8; ++ks) {
    const size_t ksb = (size_t)ks * KS_STRIDE;
    // 8 coalesced 1KB DMAs per wave (32 per wg): contiguous global, linear LDS
#pragma unroll
    for (int j = 0; j < 8; ++j)
      GLLDS(src0[j] + ksb, wdest + (unsigned)(j * 1024));
    // A fragments for this slice (drain folds into the barrier's vmcnt(0))
    const half8 a0 = *(const half8*)(ap0 + ks * 32);
    const half8 a1 = *(const half8*)(ap1 + ks * 32);
    __syncthreads();                      // compiler emits vmcnt(0) before barrier

#pragma unroll
    for (int ti = 0; ti < 8; ++ti) {
      const half8 bf = *(const half8*)(SMEM + rdoff[ti]);
      acc0[ti] = __builtin_amdgcn_mfma_f32_16x16x32_f16(a0, bf, acc0[ti], 0, 0, 0);
      acc1[ti] = __builtin_amdgcn_mfma_f32_16x16x32_f16(a1, bf, acc1[ti], 0, 0, 0);
    }
    __syncthreads();                      // stage consumed; next slice may overwrite
  }

  // ---- deposit G (pre-scaled f16) into LDS (stage region dead)
  _Float16* const Gh = (_Float16*)SMEM;   // G[qb][m][n] at (qb*32+m)*GP + n
#pragma unroll
  for (int ti = 0; ti < 8; ++ti) {
    const int n = (half * 8 + ti) * 16 + l15;
    if (n < NNc) {
#pragma unroll
      for (int rr2 = 0; rr2 < 4; ++rr2) {
        Gh[(qbR * 32 + 4 * lk + rr2) * GP + n]      = (_Float16)(acc0[ti][rr2] * invc);
        Gh[(qbR * 32 + 16 + 4 * lk + rr2) * GP + n] = (_Float16)(acc1[ti][rr2] * invc);
      }
    }
  }
  __syncthreads();

  // ---- merged epilogue (r10/r12/r13/r14 verified): full 64B lines
  {
    const int niter = (ndch + 15) >> 4;
    const int dsub = t >> 4;
    const int alpha = (t >> 2) & 3;
    const int xq = t & 3;
    const int yy = y0 + qa + 2 * alpha;
    float* ob = out + (size_t)b * ND * HW + yy * Wn + x0 + xq * 4;
    const int m0 = alpha * 8 + xq * 2;
    for (int q = 0; q < niter; ++q) {
      const int dch = q * 16 + dsub;
      if (dch < ndch) {
        const unsigned dyl = (unsigned)dch / 21u;
        const int dx = dch - (int)dyl * 21;
        const int dy = dyLo + (int)dyl;
        const int col = ((int)dyl + alpha) * NJ + xq * 2 + dx;
        floatx4 v;
        v[0] = (float)Gh[(0 * 32 + m0) * GP + col];
        v[1] = (float)Gh[(1 * 32 + m0) * GP + col];
        v[2] = (float)Gh[(0 * 32 + m0 + 1) * GP + col + 1];
        v[3] = (float)Gh[(1 * 32 + m0 + 1) * GP + col + 1];
        __builtin_nontemporal_store(v, (floatx4*)(ob + (size_t)(dy * Dn + dx) * HW));
      }
    }
  }
}

// ---------------- fallback (round-1 kernel, original layouts) -------------
constexpr int FTY = 8, FTX = 8;
constexpr int FNTY = Hn / FTY, FNTX = Wn / FTX;
constexpr int FNJ = 24, FNTILES = 36, FGP = 580;

__global__ __launch_bounds__(256, 4)
void corr_fallback(const float* __restrict__ f1, const float* __restrict__ f2,
                   float* __restrict__ out) {
  __shared__ float G[16 * FGP];
  const int bid = blockIdx.x;
  const int cls = bid & 3;
  const int t2 = bid >> 2;
  const int tx = t2 % FNTX;
  const int t3 = t2 / FNTX;
  const int ty = t3 % FNTY;
  const int b = t3 / FNTY;
  const int qa = cls >> 1, qb = cls & 1;
  const int y0 = ty * FTY, x0 = tx * FTX;
  const int lane = threadIdx.x & 63;
  const int wave = threadIdx.x >> 6;
  const int l15 = lane & 15;
  const int lk = lane >> 4;
  const float* f1b = f1 + b * (Cn * HW);
  const float* f2b = f2 + b * (Cn * HW);
  const int ay = y0 + qa + 2 * (l15 >> 2);
  const int ax = x0 + qb + 2 * (l15 & 3);
  const float* f1p = f1b + ay * Wn + ax;
  half8 afrag[8];
#pragma unroll
  for (int ks = 0; ks < 8; ++ks)
#pragma unroll
    for (int tt = 0; tt < 8; ++tt)
      afrag[ks][tt] = (_Float16)f1p[(ks * 32 + lk * 8 + tt) * HW];
  const int nt0 = wave * (FNTILES / 4);
  for (int nt = nt0; nt < nt0 + FNTILES / 4; ++nt) {
    const unsigned n = nt * 16 + l15;
    const int i = n / (unsigned)FNJ;
    const int j = n % (unsigned)FNJ;
    const int y2 = y0 - 20 + qa + 2 * i;
    const int x2 = x0 - 20 + qb + 2 * j;
    const bool inb = (y2 >= 0) & (y2 < Hn) & (x2 >= 0) & (x2 < Wn);
    const float* f2p = f2b + (inb ? (y2 * Wn + x2) : 0);
    floatx4 acc = {0.f, 0.f, 0.f, 0.f};
#pragma unroll
    for (int ks = 0; ks < 8; ++ks) {
      half8 bfrag;
#pragma unroll
      for (int tt = 0; tt < 8; ++tt) {
        const float v = f2p[(ks * 32 + lk * 8 + tt) * HW];
        bfrag[tt] = (_Float16)(inb ? v : 0.0f);
      }
      acc = __builtin_amdgcn_mfma_f32_16x16x32_f16(afrag[ks], bfrag, acc, 0, 0, 0);
    }
#pragma unroll
    for (int r = 0; r < 4; ++r)
      G[(4 * lk + r) * FGP + n] = acc[r];
  }
  __syncthreads();
  float* outb = out + b * (ND * HW);
  const float invc = 1.0f / 256.0f;
  for (int o = threadIdx.x; o < ND * 16; o += 256) {
    const int d = o >> 4;
    const int m = o & 15;
    const int dy = (unsigned)d / 21u;
    const int dx = (unsigned)d % 21u;
    const int alpha = m >> 2, beta = m & 3;
    const float val = G[m * FGP + (alpha + dy) * FNJ + (beta + dx)] * invc;
    outb[d * HW + (y0 + qa + 2 * alpha) * Wn + (x0 + qb + 2 * beta)] = val;
  }
}

extern "C" void kernel_launch(void* const* d_in, const int* in_sizes, int n_in,
                              void* d_out, int out_size, void* d_ws, size_t ws_size,
                              hipStream_t stream) {
  const float* f1 = (const float*)d_in[0];
  const float* f2 = (const float*)d_in[1];
  float* out = (float*)d_out;
  if (ws_size >= WS_NEEDED) {
    _Float16* f1t = (_Float16*)d_ws;
    _Float16* f2t2 = (_Float16*)((char*)d_ws + F1T_BYTES);
    tconv_all<<<dim3(F1_BLKS + F2_BLKS), dim3(256), 0, stream>>>(f1, f2, f1t, f2t2);
    corr10<<<dim3(Bn * 2 * NTY * NTX * 4), dim3(256), 0, stream>>>(f1t, f2t2, out);
  } else {
    corr_fallback<<<dim3(Bn * FNTY * FNTX * 4), dim3(256), 0, stream>>>(f1, f2, out);
  }
}